// Round 3
// baseline (697.668 us; speedup 1.0000x reference)
//
#include <hip/hip_runtime.h>
#include <cstdint>
#include <cstddef>

// ---------------- types ----------------
typedef __attribute__((ext_vector_type(8))) _Float16 half8;   // MFMA f16 A/B frag (4 VGPRs)
typedef __attribute__((ext_vector_type(4))) _Float16 half4;
typedef __attribute__((ext_vector_type(4))) float    floatx4; // MFMA C/D frag

static constexpr int B_ROWS = 16384;
static constexpr int IN_DIM = 256;
static constexpr int H_DIM  = 512;
static constexpr int NB     = 16;
static constexpr int KC     = 4096;   // basis K-chunk (columns of expanded A per pass)

__device__ __forceinline__ float fast_tanh(float x) {
  float ax = fabsf(x);
  float e  = __expf(2.0f * ax);             // e >= 1, inf-safe
  float t  = 1.0f - 2.0f / (e + 1.0f);
  return copysignf(t, x);
}

// async global->LDS, 16B per lane; LDS dest must be wave-uniform base + lane*16
__device__ __forceinline__ void gld16(const void* g, void* l) {
  __builtin_amdgcn_global_load_lds(
      (const __attribute__((address_space(1))) unsigned int*)g,
      (__attribute__((address_space(3))) unsigned int*)l, 16, 0, 0);
}

// ---------------- coeffs fp32 -> fp16, folding K_n = exp(-2 c_n^2) ----------------
__global__ __launch_bounds__(256) void cvt_f16_k(const float* __restrict__ src,
                                                 _Float16* __restrict__ dst,
                                                 size_t n4) {
  for (size_t i = (size_t)blockIdx.x * 256 + threadIdx.x; i < n4;
       i += (size_t)gridDim.x * 256) {
    float4 v = ((const float4*)src)[i];
    int nb = (int)((i << 2) & 15);           // n-index of element 0 (NB=16 | everything)
    half4 r;
    float c0 = -2.f + (float)(nb + 0) * (4.f / 15.f);
    float c1 = -2.f + (float)(nb + 1) * (4.f / 15.f);
    float c2 = -2.f + (float)(nb + 2) * (4.f / 15.f);
    float c3 = -2.f + (float)(nb + 3) * (4.f / 15.f);
    r[0] = (_Float16)(v.x * __expf(-2.f * c0 * c0));
    r[1] = (_Float16)(v.y * __expf(-2.f * c1 * c1));
    r[2] = (_Float16)(v.z * __expf(-2.f * c2 * c2));
    r[3] = (_Float16)(v.w * __expf(-2.f * c3 * c3));
    ((half4*)dst)[i] = r;
  }
}

// ---------------- per-column stats, two-pass (deterministic, no atomics) ----------------
__global__ __launch_bounds__(256) void stats_part_k(const float* __restrict__ X,
                                                    int rows, int cols,
                                                    double* __restrict__ ps,
                                                    double* __restrict__ ps2) {
  int c     = blockIdx.x * 64 + (threadIdx.x & 63);
  int chunk = threadIdx.x >> 6;
  int seg   = blockIdx.y;
  int rps   = rows / gridDim.y;
  int r0    = seg * rps;
  double s = 0.0, s2 = 0.0;
  for (int r = r0 + chunk; r < r0 + rps; r += 4) {
    float v = X[(size_t)r * cols + c];
    s += v; s2 += (double)v * (double)v;
  }
  __shared__ double Ls[256], Ls2[256];
  Ls[threadIdx.x] = s; Ls2[threadIdx.x] = s2;
  __syncthreads();
  if (chunk == 0) {
    int cl = threadIdx.x;
    s  = Ls[cl]  + Ls[cl + 64]  + Ls[cl + 128]  + Ls[cl + 192];
    s2 = Ls2[cl] + Ls2[cl + 64] + Ls2[cl + 128] + Ls2[cl + 192];
    ps [(size_t)seg * cols + c] = s;
    ps2[(size_t)seg * cols + c] = s2;
  }
}

__global__ void stats_final_k(const double* __restrict__ ps,
                              const double* __restrict__ ps2,
                              int segs, int cols, int rows,
                              float* __restrict__ mu, float* __restrict__ isd) {
  int c = blockIdx.x * blockDim.x + threadIdx.x;
  if (c >= cols) return;
  double s = 0.0, s2 = 0.0;
  for (int g = 0; g < segs; g++) { s += ps[(size_t)g * cols + c]; s2 += ps2[(size_t)g * cols + c]; }
  double mean = s / rows;
  double var  = (s2 - s * s / rows) / (rows - 1);   // ddof=1
  if (var < 0.0) var = 0.0;
  float sd = (float)sqrt(var);
  mu[c]  = (float)mean;
  isd[c] = 1.0f / (sd + 1e-6f);
}

// ---------------- normalize + expand 256 input-features -> fp16 basis chunk [B, 4096] ----------
// basis'_n = W * g^n with W = e^{-2x^2-8x}, g = e^{(16/15)x}  (K_n folded into coeffs)
__global__ __launch_bounds__(256) void expand_k(const float* __restrict__ src,
                                                const float* __restrict__ mu,
                                                const float* __restrict__ isd,
                                                _Float16* __restrict__ bas,
                                                int C, int i0) {
  int gid = blockIdx.x * 256 + threadIdx.x;   // B*256 threads
  int row = gid >> 8;
  int il  = gid & 255;
  int ci  = i0 + il;
  float v  = src[(size_t)row * C + ci];
  float xn = fminf(fmaxf((v - mu[ci]) * isd[ci], -3.f), 3.f);
  float W = __expf(-2.f * xn * xn - 8.f * xn);
  float g = __expf((16.f / 15.f) * xn);
  half8 h0, h1;
  float p = W;
#pragma unroll
  for (int n = 0; n < 8; n++) { h0[n] = (_Float16)p; p *= g; }
#pragma unroll
  for (int n = 0; n < 8; n++) { h1[n] = (_Float16)p; p *= g; }
  _Float16* dst = bas + (size_t)row * KC + il * 16;
  *(half8*)dst       = h0;
  *(half8*)(dst + 8) = h1;
}

// ---------------- m97-structure GEMM: C[m,n] (+)= A[m,k] * Bm[n,k] ----------------
// 128x128 tile, BK=32, unpadded LDS, all staging via global_load_lds width-16.
__global__ __launch_bounds__(256) void gemm_k(const _Float16* __restrict__ A,   // [M, KC] row-major
                                              const _Float16* __restrict__ Bm,  // [N, ldK] row-major
                                              float* __restrict__ Cout,         // [M, N]
                                              int ldK, int N, int act, int first) {
  __shared__ __align__(16) _Float16 As[128 * 32];   // 8 KB, row-major 128 x 32
  __shared__ __align__(16) _Float16 Bs[128 * 32];
  const int tid  = threadIdx.x;
  const int row0 = blockIdx.y * 128, col0 = blockIdx.x * 128;
  const int w = tid >> 6, lane = tid & 63;
  const int wm = w & 1, wn = w >> 1;
  const int lrow = lane & 15, quad = lane >> 4;

  // staging: 512 16B-chunks per tile; chunk c -> row=c>>2, seg=c&3; thread owns c=tid, c=tid+256
  const int r_a = tid >> 2, s_a = tid & 3;
  const _Float16* ga0 = A  + (size_t)(row0 + r_a)      * KC  + s_a * 8;
  const _Float16* ga1 = A  + (size_t)(row0 + r_a + 64) * KC  + s_a * 8;
  const _Float16* gb0 = Bm + (size_t)(col0 + r_a)      * ldK + s_a * 8;
  const _Float16* gb1 = Bm + (size_t)(col0 + r_a + 64) * ldK + s_a * 8;
  _Float16* la0 = &As[(size_t)tid * 8];
  _Float16* la1 = &As[(size_t)(tid + 256) * 8];
  _Float16* lb0 = &Bs[(size_t)tid * 8];
  _Float16* lb1 = &Bs[(size_t)(tid + 256) * 8];

  floatx4 acc[4][4] = {};

  for (int k0 = 0; k0 < KC; k0 += 32) {
    gld16(ga0 + k0, la0);
    gld16(ga1 + k0, la1);
    gld16(gb0 + k0, lb0);
    gld16(gb1 + k0, lb1);
    __syncthreads();                       // drains vmcnt (compiler emits waitcnt)

    half8 af[4], bf[4];
#pragma unroll
    for (int t = 0; t < 4; t++) {
      af[t] = *(const half8*)&As[(wm * 64 + t * 16 + lrow) * 32 + quad * 8];
      bf[t] = *(const half8*)&Bs[(wn * 64 + t * 16 + lrow) * 32 + quad * 8];
    }
#pragma unroll
    for (int tm = 0; tm < 4; tm++)
#pragma unroll
      for (int tn = 0; tn < 4; tn++)
        acc[tm][tn] = __builtin_amdgcn_mfma_f32_16x16x32_f16(af[tm], bf[tn], acc[tm][tn], 0, 0, 0);
    __syncthreads();
  }

  // epilogue: C/D layout col=lane&15, row=quad*4+reg (m89/m91-verified)
#pragma unroll
  for (int tm = 0; tm < 4; tm++) {
#pragma unroll
    for (int tn = 0; tn < 4; tn++) {
      int gcol = col0 + wn * 64 + tn * 16 + lrow;
#pragma unroll
      for (int r = 0; r < 4; r++) {
        int grow = row0 + wm * 64 + tm * 16 + quad * 4 + r;
        size_t idx = (size_t)grow * N + gcol;
        float v = acc[tm][tn][r];
        if (!first) v += Cout[idx];
        if (act) v = fast_tanh(v);
        Cout[idx] = v;
      }
    }
  }
}

// ---------------- layer 3 (out dim 1) + skip, fp32, normalize fused ----------------
__global__ __launch_bounds__(256) void layer3_k(const float* __restrict__ H2,
                                                const float* __restrict__ mu,
                                                const float* __restrict__ isd,
                                                const float* __restrict__ C3,
                                                const float* __restrict__ X,
                                                const float* __restrict__ SW,
                                                const float* __restrict__ SB,
                                                float* __restrict__ OUT) {
  int w = threadIdx.x >> 6, lane = threadIdx.x & 63;
  float Kn[NB];
#pragma unroll
  for (int n = 0; n < NB; n++) {
    float c = -2.f + (float)n * (4.f / 15.f);
    Kn[n] = __expf(-2.f * c * c);
  }
  float sb0 = SB[0];
  int row_base = blockIdx.x * 16 + w * 4;
  for (int r = 0; r < 4; r++) {
    int row = row_base + r;
    float s = 0.f;
#pragma unroll
    for (int j = 0; j < 8; j++) {
      int i = lane + 64 * j;
      float hv = H2[(size_t)row * H_DIM + i];
      float xn = fminf(fmaxf((hv - mu[i]) * isd[i], -3.f), 3.f);
      float Wf = __expf(-2.f * xn * xn - 8.f * xn);
      float gf = __expf((16.f / 15.f) * xn);
      const floatx4* cp = (const floatx4*)(C3 + (size_t)i * NB);
      floatx4 c0 = cp[0], c1 = cp[1], c2 = cp[2], c3 = cp[3];
      float p = Wf;
#pragma unroll
      for (int n = 0; n < 4; n++) { s += p * Kn[n]      * c0[n]; p *= gf; }
#pragma unroll
      for (int n = 0; n < 4; n++) { s += p * Kn[n + 4]  * c1[n]; p *= gf; }
#pragma unroll
      for (int n = 0; n < 4; n++) { s += p * Kn[n + 8]  * c2[n]; p *= gf; }
#pragma unroll
      for (int n = 0; n < 4; n++) { s += p * Kn[n + 12] * c3[n]; p *= gf; }
    }
#pragma unroll
    for (int j = 0; j < 4; j++) {
      int i = lane + 64 * j;
      s += X[(size_t)row * IN_DIM + i] * SW[i];
    }
#pragma unroll
    for (int off = 32; off > 0; off >>= 1) s += __shfl_down(s, off);
    if (lane == 0) OUT[row] = s + sb0;
  }
}

// ---------------- launcher ----------------
extern "C" void kernel_launch(void* const* d_in, const int* in_sizes, int n_in,
                              void* d_out, int out_size, void* d_ws, size_t ws_size,
                              hipStream_t stream) {
  const float* x  = (const float*)d_in[0];   // [16384, 256]
  const float* c1 = (const float*)d_in[1];   // [512, 256, 16]
  const float* c2 = (const float*)d_in[2];   // [512, 512, 16]
  const float* c3 = (const float*)d_in[3];   // [1, 512, 16]
  const float* sw = (const float*)d_in[4];   // [1, 256]
  const float* sb = (const float*)d_in[5];   // [1]
  float* out = (float*)d_out;

  const int B = B_ROWS, IN = IN_DIM, H = H_DIM;

  char* ws = (char*)d_ws;
  size_t off = 0;
  auto alloc = [&](size_t bytes) -> void* {
    void* p = ws + off;
    off += (bytes + 255) & ~(size_t)255;
    return p;
  };
  _Float16* C1h = (_Float16*)alloc((size_t)H * IN * NB * 2);  //   4 MB
  _Float16* C2h = (_Float16*)alloc((size_t)H * H  * NB * 2);  //   8 MB
  float* H1 = (float*)alloc((size_t)B * H * 4);               //  32 MB
  float* H2 = (float*)alloc((size_t)B * H * 4);               //  32 MB
  _Float16* BAS = (_Float16*)alloc((size_t)B * KC * 2);       // 128 MB (reused per chunk)
  double* ps  = (double*)alloc(32 * 512 * 8);
  double* ps2 = (double*)alloc(32 * 512 * 8);
  float* mu  = (float*)alloc(512 * 4);
  float* isd = (float*)alloc(512 * 4);

  // coeff conversion (K_n folded in)
  cvt_f16_k<<<1024, 256, 0, stream>>>(c1, C1h, (size_t)H * IN * NB / 4);
  cvt_f16_k<<<1024, 256, 0, stream>>>(c2, C2h, (size_t)H * H  * NB / 4);

  // ---- layer 1 (K = 4096, one chunk) ----
  stats_part_k<<<dim3(IN / 64, 32), 256, 0, stream>>>(x, B, IN, ps, ps2);
  stats_final_k<<<1, 256, 0, stream>>>(ps, ps2, 32, IN, B, mu, isd);
  expand_k<<<B, 256, 0, stream>>>(x, mu, isd, BAS, IN, 0);
  gemm_k<<<dim3(H / 128, B / 128), 256, 0, stream>>>(BAS, C1h, H1, KC, H, 1, 1);

  // ---- layer 2 (K = 8192, two chunks accumulated) ----
  stats_part_k<<<dim3(H / 64, 32), 256, 0, stream>>>(H1, B, H, ps, ps2);
  stats_final_k<<<2, 256, 0, stream>>>(ps, ps2, 32, H, B, mu, isd);
  expand_k<<<B, 256, 0, stream>>>(H1, mu, isd, BAS, H, 0);
  gemm_k<<<dim3(H / 128, B / 128), 256, 0, stream>>>(BAS, C2h, H2, (size_t)H * NB, H, 0, 1);
  expand_k<<<B, 256, 0, stream>>>(H1, mu, isd, BAS, H, 256);
  gemm_k<<<dim3(H / 128, B / 128), 256, 0, stream>>>(BAS, C2h + KC, H2, (size_t)H * NB, H, 1, 0);

  // ---- layer 3 + skip (normalize fused) ----
  stats_part_k<<<dim3(H / 64, 32), 256, 0, stream>>>(H2, B, H, ps, ps2);
  stats_final_k<<<2, 256, 0, stream>>>(ps, ps2, 32, H, B, mu, isd);
  layer3_k<<<B / 16, 256, 0, stream>>>(H2, mu, isd, c3, x, sw, sb, out);
}

// Round 4
// 532.953 us; speedup vs baseline: 1.3091x; 1.3091x over previous
//
#include <hip/hip_runtime.h>
#include <cstdint>
#include <cstddef>

// ---------------- types ----------------
typedef __attribute__((ext_vector_type(8))) _Float16 half8;   // MFMA f16 A/B frag (4 VGPRs)
typedef __attribute__((ext_vector_type(4))) _Float16 half4;
typedef __attribute__((ext_vector_type(4))) float    floatx4; // MFMA C/D frag

static constexpr int B_ROWS = 16384;
static constexpr int IN_DIM = 256;
static constexpr int H_DIM  = 512;
static constexpr int NB     = 16;

__device__ __forceinline__ float fast_tanh(float x) {
  float ax = fabsf(x);
  float e  = __expf(2.0f * ax);             // e >= 1, inf-safe
  float t  = 1.0f - 2.0f / (e + 1.0f);
  return copysignf(t, x);
}

// async global->LDS, 16B per lane; LDS dest must be wave-uniform base + lane*16
__device__ __forceinline__ void gld16(const void* g, void* l) {
  __builtin_amdgcn_global_load_lds(
      (const __attribute__((address_space(1))) unsigned int*)g,
      (__attribute__((address_space(3))) unsigned int*)l, 16, 0, 0);
}

// ---------------- coeffs fp32 -> fp16, folding K_n = exp(-2 c_n^2) ----------------
__global__ __launch_bounds__(256) void cvt_f16_k(const float* __restrict__ src,
                                                 _Float16* __restrict__ dst,
                                                 size_t n4) {
  for (size_t i = (size_t)blockIdx.x * 256 + threadIdx.x; i < n4;
       i += (size_t)gridDim.x * 256) {
    float4 v = ((const float4*)src)[i];
    int nb = (int)((i << 2) & 15);           // n-index of element 0 (NB=16 | everything)
    half4 r;
    float c0 = -2.f + (float)(nb + 0) * (4.f / 15.f);
    float c1 = -2.f + (float)(nb + 1) * (4.f / 15.f);
    float c2 = -2.f + (float)(nb + 2) * (4.f / 15.f);
    float c3 = -2.f + (float)(nb + 3) * (4.f / 15.f);
    r[0] = (_Float16)(v.x * __expf(-2.f * c0 * c0));
    r[1] = (_Float16)(v.y * __expf(-2.f * c1 * c1));
    r[2] = (_Float16)(v.z * __expf(-2.f * c2 * c2));
    r[3] = (_Float16)(v.w * __expf(-2.f * c3 * c3));
    ((half4*)dst)[i] = r;
  }
}

// ---------------- per-column stats, two-pass (deterministic, no atomics) ----------------
__global__ __launch_bounds__(256) void stats_part_k(const float* __restrict__ X,
                                                    int rows, int cols,
                                                    double* __restrict__ ps,
                                                    double* __restrict__ ps2) {
  int c     = blockIdx.x * 64 + (threadIdx.x & 63);
  int chunk = threadIdx.x >> 6;
  int seg   = blockIdx.y;
  int rps   = rows / gridDim.y;
  int r0    = seg * rps;
  double s = 0.0, s2 = 0.0;
  for (int r = r0 + chunk; r < r0 + rps; r += 4) {
    float v = X[(size_t)r * cols + c];
    s += v; s2 += (double)v * (double)v;
  }
  __shared__ double Ls[256], Ls2[256];
  Ls[threadIdx.x] = s; Ls2[threadIdx.x] = s2;
  __syncthreads();
  if (chunk == 0) {
    int cl = threadIdx.x;
    s  = Ls[cl]  + Ls[cl + 64]  + Ls[cl + 128]  + Ls[cl + 192];
    s2 = Ls2[cl] + Ls2[cl + 64] + Ls2[cl + 128] + Ls2[cl + 192];
    ps [(size_t)seg * cols + c] = s;
    ps2[(size_t)seg * cols + c] = s2;
  }
}

__global__ void stats_final_k(const double* __restrict__ ps,
                              const double* __restrict__ ps2,
                              int segs, int cols, int rows,
                              float* __restrict__ mu, float* __restrict__ isd) {
  int c = blockIdx.x * blockDim.x + threadIdx.x;
  if (c >= cols) return;
  double s = 0.0, s2 = 0.0;
  for (int g = 0; g < segs; g++) { s += ps[(size_t)g * cols + c]; s2 += ps2[(size_t)g * cols + c]; }
  double mean = s / rows;
  double var  = (s2 - s * s / rows) / (rows - 1);   // ddof=1
  if (var < 0.0) var = 0.0;
  float sd = (float)sqrt(var);
  mu[c]  = (float)mean;
  isd[c] = 1.0f / (sd + 1e-6f);
}

// ---------------- fused normalize+expand+GEMM+tanh ----------------
// H[b, o] = tanh( sum_k basis(xn[b, k/16])_[k%16] * Cb[o, k] ),  K = C*16
// 128x256 macro-tile, 512 threads (8 waves 2x4), grid (B/128, 2) = 256 blocks = 1/CU.
// Basis generated in-kernel (2 exps/xn, once per col-half); LDS double-buffered,
// ONE barrier per K-step: DMA for k+1 issued before MFMA of k -> drain hidden.
__global__ __launch_bounds__(512) void kan_gemm_fused(const float* __restrict__ X,   // [B, C]
                                                      const float* __restrict__ mu,
                                                      const float* __restrict__ isd,
                                                      const _Float16* __restrict__ Bm, // [512, C*16]
                                                      float* __restrict__ Hout,        // [B, 512]
                                                      int C) {
  const int K = C << 4;
  const int steps = K >> 5;                 // BK = 32
  __shared__ __align__(16) _Float16 As[2][128 * 32];   // 16 KB
  __shared__ __align__(16) _Float16 Bs[2][256 * 32];   // 32 KB
  const int tid  = threadIdx.x;
  const int w = tid >> 6, lane = tid & 63;
  const int wm = w & 1, wn = w >> 1;        // 2 (rows) x 4 (cols) wave grid
  const int lrow = lane & 15, quad = lane >> 4;
  const int row0 = blockIdx.x * 128;
  const int col0 = blockIdx.y * 256;

  // B staging: 1024 chunks of 16B per K-step; chunk c -> row=c>>2, seg=c&3.
  // thread owns c = tid and c = tid + 512 (lane-contiguous per wave for gld16).
  const int br = tid >> 2, bsg = tid & 3;
  const _Float16* gB0 = Bm + (size_t)(col0 + br)       * K + bsg * 8;
  const _Float16* gB1 = Bm + (size_t)(col0 + br + 128) * K + bsg * 8;

  // A expansion: threads 0..255: row = t>>1, half h = t&1 (k-local 16h..16h+15)
  const int erow = tid >> 1, eh = tid & 1;
  const float* xp = X + (size_t)(row0 + erow) * C + eh;   // xn(k) = xp[2k]

  floatx4 acc[4][4] = {};
  float xn_next = 0.f;

  auto expand_store = [&](float v, int ci, _Float16* dst) {
    float xn = fminf(fmaxf((v - mu[ci]) * isd[ci], -3.f), 3.f);
    float Wv = __expf(-2.f * xn * xn - 8.f * xn);
    float g  = __expf((16.f / 15.f) * xn);
    half8 h0, h1;
    float p = Wv;
#pragma unroll
    for (int n = 0; n < 8; n++) { h0[n] = (_Float16)p; p *= g; }
#pragma unroll
    for (int n = 0; n < 8; n++) { h1[n] = (_Float16)p; p *= g; }
    *(half8*)dst       = h0;
    *(half8*)(dst + 8) = h1;
  };

  // ---- prologue: fill buffer 0 ----
  gld16(gB0, &Bs[0][tid * 8]);
  gld16(gB1, &Bs[0][(tid + 512) * 8]);
  if (tid < 256) {
    expand_store(xp[0], eh, &As[0][erow * 32 + eh * 16]);
    xn_next = xp[2];                        // prefetch for step 1
  }
  __syncthreads();

  // ---- main loop: one barrier per K-step ----
  for (int k = 0; k < steps; k++) {
    const int buf = k & 1, nb = buf ^ 1;
    if (k + 1 < steps) {
      gld16(gB0 + (size_t)(k + 1) * 32, &Bs[nb][tid * 8]);
      gld16(gB1 + (size_t)(k + 1) * 32, &Bs[nb][(tid + 512) * 8]);
      if (tid < 256) {
        expand_store(xn_next, 2 * (k + 1) + eh, &As[nb][erow * 32 + eh * 16]);
        if (k + 2 < steps) xn_next = xp[2 * (k + 2)];
      }
    }
    half8 af[4], bf[4];
#pragma unroll
    for (int t = 0; t < 4; t++) {
      af[t] = *(const half8*)&As[buf][(wm * 64 + t * 16 + lrow) * 32 + quad * 8];
      bf[t] = *(const half8*)&Bs[buf][(wn * 64 + t * 16 + lrow) * 32 + quad * 8];
    }
#pragma unroll
    for (int tm = 0; tm < 4; tm++)
#pragma unroll
      for (int tn = 0; tn < 4; tn++)
        acc[tm][tn] = __builtin_amdgcn_mfma_f32_16x16x32_f16(af[tm], bf[tn], acc[tm][tn], 0, 0, 0);
    __syncthreads();
  }

  // ---- epilogue: C/D layout col=lane&15, row=quad*4+reg; fused tanh ----
#pragma unroll
  for (int tm = 0; tm < 4; tm++) {
#pragma unroll
    for (int tn = 0; tn < 4; tn++) {
      int gcol = col0 + wn * 64 + tn * 16 + lrow;
#pragma unroll
      for (int r = 0; r < 4; r++) {
        int grow = row0 + wm * 64 + tm * 16 + quad * 4 + r;
        Hout[(size_t)grow * H_DIM + gcol] = fast_tanh(acc[tm][tn][r]);
      }
    }
  }
}

// ---------------- layer 3 (out dim 1) + skip, fp32, normalize fused ----------------
__global__ __launch_bounds__(256) void layer3_k(const float* __restrict__ H2,
                                                const float* __restrict__ mu,
                                                const float* __restrict__ isd,
                                                const float* __restrict__ C3,
                                                const float* __restrict__ X,
                                                const float* __restrict__ SW,
                                                const float* __restrict__ SB,
                                                float* __restrict__ OUT) {
  int w = threadIdx.x >> 6, lane = threadIdx.x & 63;
  float Kn[NB];
#pragma unroll
  for (int n = 0; n < NB; n++) {
    float c = -2.f + (float)n * (4.f / 15.f);
    Kn[n] = __expf(-2.f * c * c);
  }
  float sb0 = SB[0];
  int row_base = blockIdx.x * 16 + w * 4;
  for (int r = 0; r < 4; r++) {
    int row = row_base + r;
    float s = 0.f;
#pragma unroll
    for (int j = 0; j < 8; j++) {
      int i = lane + 64 * j;
      float hv = H2[(size_t)row * H_DIM + i];
      float xn = fminf(fmaxf((hv - mu[i]) * isd[i], -3.f), 3.f);
      float Wf = __expf(-2.f * xn * xn - 8.f * xn);
      float gf = __expf((16.f / 15.f) * xn);
      const floatx4* cp = (const floatx4*)(C3 + (size_t)i * NB);
      floatx4 c0 = cp[0], c1 = cp[1], c2 = cp[2], c3 = cp[3];
      float p = Wf;
#pragma unroll
      for (int n = 0; n < 4; n++) { s += p * Kn[n]      * c0[n]; p *= gf; }
#pragma unroll
      for (int n = 0; n < 4; n++) { s += p * Kn[n + 4]  * c1[n]; p *= gf; }
#pragma unroll
      for (int n = 0; n < 4; n++) { s += p * Kn[n + 8]  * c2[n]; p *= gf; }
#pragma unroll
      for (int n = 0; n < 4; n++) { s += p * Kn[n + 12] * c3[n]; p *= gf; }
    }
#pragma unroll
    for (int j = 0; j < 4; j++) {
      int i = lane + 64 * j;
      s += X[(size_t)row * IN_DIM + i] * SW[i];
    }
#pragma unroll
    for (int off = 32; off > 0; off >>= 1) s += __shfl_down(s, off);
    if (lane == 0) OUT[row] = s + sb0;
  }
}

// ---------------- launcher ----------------
extern "C" void kernel_launch(void* const* d_in, const int* in_sizes, int n_in,
                              void* d_out, int out_size, void* d_ws, size_t ws_size,
                              hipStream_t stream) {
  const float* x  = (const float*)d_in[0];   // [16384, 256]
  const float* c1 = (const float*)d_in[1];   // [512, 256, 16]
  const float* c2 = (const float*)d_in[2];   // [512, 512, 16]
  const float* c3 = (const float*)d_in[3];   // [1, 512, 16]
  const float* sw = (const float*)d_in[4];   // [1, 256]
  const float* sb = (const float*)d_in[5];   // [1]
  float* out = (float*)d_out;

  const int B = B_ROWS, IN = IN_DIM, H = H_DIM;

  char* ws = (char*)d_ws;
  size_t off = 0;
  auto alloc = [&](size_t bytes) -> void* {
    void* p = ws + off;
    off += (bytes + 255) & ~(size_t)255;
    return p;
  };
  _Float16* C1h = (_Float16*)alloc((size_t)H * IN * NB * 2);  //  4 MB
  _Float16* C2h = (_Float16*)alloc((size_t)H * H  * NB * 2);  //  8 MB
  float* H1 = (float*)alloc((size_t)B * H * 4);               // 32 MB
  float* H2 = (float*)alloc((size_t)B * H * 4);               // 32 MB
  double* ps  = (double*)alloc(32 * 512 * 8);
  double* ps2 = (double*)alloc(32 * 512 * 8);
  float* mu  = (float*)alloc(512 * 4);
  float* isd = (float*)alloc(512 * 4);

  // coeff conversion (K_n folded in)
  cvt_f16_k<<<1024, 256, 0, stream>>>(c1, C1h, (size_t)H * IN * NB / 4);
  cvt_f16_k<<<1024, 256, 0, stream>>>(c2, C2h, (size_t)H * H  * NB / 4);

  // ---- layer 1 (C=256, K=4096) ----
  stats_part_k<<<dim3(IN / 64, 32), 256, 0, stream>>>(x, B, IN, ps, ps2);
  stats_final_k<<<1, 256, 0, stream>>>(ps, ps2, 32, IN, B, mu, isd);
  kan_gemm_fused<<<dim3(B / 128, 2), 512, 0, stream>>>(x, mu, isd, C1h, H1, IN);

  // ---- layer 2 (C=512, K=8192, single dispatch) ----
  stats_part_k<<<dim3(H / 64, 32), 256, 0, stream>>>(H1, B, H, ps, ps2);
  stats_final_k<<<2, 256, 0, stream>>>(ps, ps2, 32, H, B, mu, isd);
  kan_gemm_fused<<<dim3(B / 128, 2), 512, 0, stream>>>(H1, mu, isd, C2h, H2, H);

  // ---- layer 3 + skip (normalize fused) ----
  stats_part_k<<<dim3(H / 64, 32), 256, 0, stream>>>(H2, B, H, ps, ps2);
  stats_final_k<<<2, 256, 0, stream>>>(ps, ps2, 32, H, B, mu, isd);
  layer3_k<<<B / 16, 256, 0, stream>>>(H2, mu, isd, c3, x, sw, sb, out);
}